// Round 1
// baseline (1131.903 us; speedup 1.0000x reference)
//
#include <hip/hip_runtime.h>
#include <hip/hip_bf16.h>
#include <math.h>

#define T_TOKENS 2048
#define HID 1024
#define INTER 2048
#define NE 8

// ---------------- workspace layout (bytes) ----------------
// total required: 50,462,720 bytes (~48.2 MiB)
#define WS_COUNTS   0u                         // int[8]
#define WS_CURSORS  32u                        // int[8]
#define WS_OFFSETS  64u                        // int[8]
#define WS_SEL      128u                       // int[2048*2]
#define WS_SELW     16512u                     // float[2048*2]
#define WS_ROWTOK   32896u                     // int[4096]
#define WS_ROWW     49280u                     // float[4096]
#define WS_TOKROWS  65664u                     // int[2048*2]
#define WS_Y        131072u                    // float[4096*2048]  (33.55 MB)
#define WS_Z        (131072u + 4096u*2048u*4u) // float[4096*1024]  (16.78 MB)

// ---------------- router: gating GEMV + softmax + top2 ----------------
// one wave (64 lanes) per token; block = 4 waves
__global__ __launch_bounds__(256) void moe_router(
    const float* __restrict__ x, const float* __restrict__ rw,
    int* __restrict__ counts, int* __restrict__ sel, float* __restrict__ selw)
{
    int wave = threadIdx.x >> 6;
    int lane = threadIdx.x & 63;
    int t = blockIdx.x * 4 + wave;
    if (t >= T_TOKENS) return;

    const float4* x4  = (const float4*)x + (size_t)t * (HID / 4);
    const float4* rw4 = (const float4*)rw;

    float acc[NE];
#pragma unroll
    for (int e = 0; e < NE; ++e) acc[e] = 0.f;

#pragma unroll
    for (int q = 0; q < 4; ++q) {
        int idx = q * 64 + lane;          // 256 float4 per row
        float4 xv = x4[idx];
#pragma unroll
        for (int e = 0; e < NE; ++e) {
            float4 rv = rw4[e * (HID / 4) + idx];
            acc[e] += xv.x * rv.x + xv.y * rv.y + xv.z * rv.z + xv.w * rv.w;
        }
    }
#pragma unroll
    for (int off = 32; off; off >>= 1)
#pragma unroll
        for (int e = 0; e < NE; ++e) acc[e] += __shfl_xor(acc[e], off, 64);

    if (lane == 0) {
        float m = acc[0];
#pragma unroll
        for (int e = 1; e < NE; ++e) m = fmaxf(m, acc[e]);
        float p[NE], s = 0.f;
#pragma unroll
        for (int e = 0; e < NE; ++e) { p[e] = expf(acc[e] - m); s += p[e]; }
        float inv = 1.f / s;
        int i0 = 0;
#pragma unroll
        for (int e = 1; e < NE; ++e) if (p[e] > p[i0]) i0 = e;
        int i1 = (i0 == 0) ? 1 : 0;
#pragma unroll
        for (int e = 0; e < NE; ++e) if (e != i0 && p[e] > p[i1]) i1 = e;
        sel[t * 2 + 0] = i0; selw[t * 2 + 0] = p[i0] * inv;
        sel[t * 2 + 1] = i1; selw[t * 2 + 1] = p[i1] * inv;
        atomicAdd(&counts[i0], 1);
        atomicAdd(&counts[i1], 1);
    }
}

// ---------------- tiny scan: offsets = exclusive_scan(counts) ----------------
__global__ void moe_scan(const int* __restrict__ counts,
                         int* __restrict__ offsets, int* __restrict__ cursors)
{
    if (threadIdx.x == 0 && blockIdx.x == 0) {
        int off = 0;
        for (int e = 0; e < NE; ++e) {
            offsets[e] = off;
            off += counts[e];
            cursors[e] = 0;
        }
    }
}

// ---------------- slot assignment: token -> expert-grouped rows ----------------
__global__ __launch_bounds__(256) void moe_assign(
    const int* __restrict__ sel, const float* __restrict__ selw,
    const int* __restrict__ offsets, int* __restrict__ cursors,
    int* __restrict__ row_token, float* __restrict__ row_w,
    int* __restrict__ token_rows)
{
    int t = blockIdx.x * 256 + threadIdx.x;
    if (t >= T_TOKENS) return;
#pragma unroll
    for (int k = 0; k < 2; ++k) {
        int e = sel[t * 2 + k];
        int slot = atomicAdd(&cursors[e], 1);
        int r = offsets[e] + slot;
        row_token[r] = t;
        row_w[r] = selw[t * 2 + k];
        token_rows[t * 2 + k] = r;
    }
}

// ---------------- GEMM1: y[r, i] = silu(x[tok]*W1g[e,i]) * (x[tok]*W1u[e,i]) ----------------
// 64x64 output tile, K-chunks of 16, 256 threads, 4x4 micro-tile, dual acc (gate+up)
__global__ __launch_bounds__(256) void moe_gemm1(
    const float* __restrict__ x, const float* __restrict__ w1,
    const int* __restrict__ row_token, const int* __restrict__ counts,
    const int* __restrict__ offsets, float* __restrict__ y)
{
    int e = blockIdx.z;
    int cnt = counts[e];
    int row0 = blockIdx.y * 64;
    if (row0 >= cnt) return;
    int col0 = blockIdx.x * 64;
    int base = offsets[e];

    __shared__ float As[16][64];
    __shared__ float Bg[16][64];
    __shared__ float Bu[16][64];

    int tid = threadIdx.x;
    int kq = tid & 3;          // f4 index along k (global coalescing: 64B segments)
    int sr = tid >> 2;         // row within tile (0..63)

    int ar = row0 + sr; if (ar > cnt - 1) ar = cnt - 1;   // clamp (dup rows, stores guarded)
    const float* aptr = x  + (size_t)row_token[base + ar] * HID + kq * 4;
    const float* bgp  = w1 + ((size_t)e * 2 * INTER + col0 + sr) * HID + kq * 4;
    const float* bup  = bgp + (size_t)INTER * HID;

    int tx = tid & 15, ty = tid >> 4;
    float accg[4][4] = {}, accu[4][4] = {};

    for (int k0 = 0; k0 < HID; k0 += 16) {
        float4 av  = *(const float4*)(aptr + k0);
        float4 bgv = *(const float4*)(bgp  + k0);
        float4 buv = *(const float4*)(bup  + k0);
        __syncthreads();
        As[kq*4+0][sr] = av.x;  As[kq*4+1][sr] = av.y;  As[kq*4+2][sr] = av.z;  As[kq*4+3][sr] = av.w;
        Bg[kq*4+0][sr] = bgv.x; Bg[kq*4+1][sr] = bgv.y; Bg[kq*4+2][sr] = bgv.z; Bg[kq*4+3][sr] = bgv.w;
        Bu[kq*4+0][sr] = buv.x; Bu[kq*4+1][sr] = buv.y; Bu[kq*4+2][sr] = buv.z; Bu[kq*4+3][sr] = buv.w;
        __syncthreads();
#pragma unroll
        for (int kk = 0; kk < 16; ++kk) {
            float4 a4 = *(const float4*)&As[kk][ty * 4];
            float4 g4 = *(const float4*)&Bg[kk][tx * 4];
            float4 u4 = *(const float4*)&Bu[kk][tx * 4];
            float a[4] = {a4.x, a4.y, a4.z, a4.w};
            float g[4] = {g4.x, g4.y, g4.z, g4.w};
            float u[4] = {u4.x, u4.y, u4.z, u4.w};
#pragma unroll
            for (int m = 0; m < 4; ++m)
#pragma unroll
                for (int n = 0; n < 4; ++n) {
                    accg[m][n] = fmaf(a[m], g[n], accg[m][n]);
                    accu[m][n] = fmaf(a[m], u[n], accu[m][n]);
                }
        }
    }

#pragma unroll
    for (int m = 0; m < 4; ++m) {
        int r = row0 + ty * 4 + m;
        if (r >= cnt) continue;
        float4 o;
        float* op = (float*)&o;
#pragma unroll
        for (int n = 0; n < 4; ++n) {
            float g = accg[m][n];
            float s = g / (1.f + expf(-g));   // silu
            op[n] = s * accu[m][n];
        }
        *(float4*)(y + (size_t)(base + r) * INTER + col0 + tx * 4) = o;
    }
}

// ---------------- GEMM2: z[r, h] = row_w[r] * sum_i y[r,i] * w2[e,h,i] ----------------
__global__ __launch_bounds__(256) void moe_gemm2(
    const float* __restrict__ y, const float* __restrict__ w2,
    const float* __restrict__ row_w, const int* __restrict__ counts,
    const int* __restrict__ offsets, float* __restrict__ z)
{
    int e = blockIdx.z;
    int cnt = counts[e];
    int row0 = blockIdx.y * 64;
    if (row0 >= cnt) return;
    int col0 = blockIdx.x * 64;   // over H
    int base = offsets[e];

    __shared__ float As[16][64];
    __shared__ float Bs[16][64];

    int tid = threadIdx.x;
    int kq = tid & 3;
    int sr = tid >> 2;

    int ar = row0 + sr; if (ar > cnt - 1) ar = cnt - 1;
    const float* aptr = y  + (size_t)(base + ar) * INTER + kq * 4;
    const float* bptr = w2 + ((size_t)e * HID + col0 + sr) * INTER + kq * 4;

    int tx = tid & 15, ty = tid >> 4;
    float acc[4][4] = {};

    for (int k0 = 0; k0 < INTER; k0 += 16) {
        float4 av = *(const float4*)(aptr + k0);
        float4 bv = *(const float4*)(bptr + k0);
        __syncthreads();
        As[kq*4+0][sr] = av.x; As[kq*4+1][sr] = av.y; As[kq*4+2][sr] = av.z; As[kq*4+3][sr] = av.w;
        Bs[kq*4+0][sr] = bv.x; Bs[kq*4+1][sr] = bv.y; Bs[kq*4+2][sr] = bv.z; Bs[kq*4+3][sr] = bv.w;
        __syncthreads();
#pragma unroll
        for (int kk = 0; kk < 16; ++kk) {
            float4 a4 = *(const float4*)&As[kk][ty * 4];
            float4 b4 = *(const float4*)&Bs[kk][tx * 4];
            float a[4] = {a4.x, a4.y, a4.z, a4.w};
            float b[4] = {b4.x, b4.y, b4.z, b4.w};
#pragma unroll
            for (int m = 0; m < 4; ++m)
#pragma unroll
                for (int n = 0; n < 4; ++n)
                    acc[m][n] = fmaf(a[m], b[n], acc[m][n]);
        }
    }

#pragma unroll
    for (int m = 0; m < 4; ++m) {
        int r = row0 + ty * 4 + m;
        if (r >= cnt) continue;
        float wgt = row_w[base + r];
        float4 o;
        float* op = (float*)&o;
#pragma unroll
        for (int n = 0; n < 4; ++n) op[n] = acc[m][n] * wgt;
        *(float4*)(z + (size_t)(base + r) * HID + col0 + tx * 4) = o;
    }
}

// ---------------- combine: out[t] = z[r0] + z[r1]  (weights already folded) ----------------
__global__ __launch_bounds__(256) void moe_combine(
    const float* __restrict__ z, const int* __restrict__ token_rows,
    float* __restrict__ out)
{
    int total = T_TOKENS * (HID / 4);
    for (int idx = blockIdx.x * 256 + threadIdx.x; idx < total; idx += gridDim.x * 256) {
        int t  = idx >> 8;           // HID/4 = 256
        int h4 = idx & 255;
        int r0 = token_rows[t * 2 + 0];
        int r1 = token_rows[t * 2 + 1];
        const float4* z4 = (const float4*)z;
        float4 a = z4[(size_t)r0 * 256 + h4];
        float4 b = z4[(size_t)r1 * 256 + h4];
        float4 o = {a.x + b.x, a.y + b.y, a.z + b.z, a.w + b.w};
        ((float4*)out)[(size_t)t * 256 + h4] = o;
    }
}

extern "C" void kernel_launch(void* const* d_in, const int* in_sizes, int n_in,
                              void* d_out, int out_size, void* d_ws, size_t ws_size,
                              hipStream_t stream) {
    const float* x  = (const float*)d_in[0];   // [1,2048,1024]
    const float* w1 = (const float*)d_in[1];   // [8,4096,1024]
    const float* w2 = (const float*)d_in[2];   // [8,1024,2048]
    const float* rw = (const float*)d_in[3];   // [8,1024]
    float* out = (float*)d_out;                // [1,2048,1024]

    char* ws = (char*)d_ws;
    int*   counts     = (int*)(ws + WS_COUNTS);
    int*   cursors    = (int*)(ws + WS_CURSORS);
    int*   offsets    = (int*)(ws + WS_OFFSETS);
    int*   sel        = (int*)(ws + WS_SEL);
    float* selw       = (float*)(ws + WS_SELW);
    int*   row_token  = (int*)(ws + WS_ROWTOK);
    float* row_w      = (float*)(ws + WS_ROWW);
    int*   token_rows = (int*)(ws + WS_TOKROWS);
    float* y          = (float*)(ws + WS_Y);
    float* z          = (float*)(ws + WS_Z);

    hipMemsetAsync(ws, 0, 128, stream);  // counts + cursors (+offsets, rewritten)

    moe_router<<<T_TOKENS / 4, 256, 0, stream>>>(x, rw, counts, sel, selw);
    moe_scan<<<1, 64, 0, stream>>>(counts, offsets, cursors);
    moe_assign<<<T_TOKENS / 256, 256, 0, stream>>>(sel, selw, offsets, cursors,
                                                   row_token, row_w, token_rows);
    moe_gemm1<<<dim3(INTER / 64, T_TOKENS / 64, NE), 256, 0, stream>>>(
        x, w1, row_token, counts, offsets, y);
    moe_gemm2<<<dim3(HID / 64, T_TOKENS / 64, NE), 256, 0, stream>>>(
        y, w2, row_w, counts, offsets, z);
    moe_combine<<<1024, 256, 0, stream>>>(z, token_rows, out);
}

// Round 3
// 443.698 us; speedup vs baseline: 2.5511x; 2.5511x over previous
//
#include <hip/hip_runtime.h>
#include <hip/hip_bf16.h>
#include <math.h>

#define T_TOKENS 2048
#define HID 1024
#define INTER 2048
#define NE 8

typedef __attribute__((ext_vector_type(8))) __bf16 bf16x8;
typedef __attribute__((ext_vector_type(4))) float f32x4;

// ---------------- workspace layout (bytes) ----------------
// total: ~37.9 MB (within the ~50 MB proven-safe size from R1)
#define WS_COUNTS   0u          // int[8]
#define WS_CURSORS  32u         // int[8]
#define WS_OFFSETS  64u         // int[8]
#define WS_SEL      128u        // int[4096]
#define WS_SELW     16512u      // float[4096]
#define WS_ROWTOK   32896u      // int[4096]
#define WS_ROWW     49280u      // float[4096]
#define WS_TOKROWS  65664u      // int[4096]
#define WS_XB       131072u                      // bf16[2048*1024]  (4 MB)
#define WS_Y        (131072u + 4194304u)         // bf16[4096*2048]  (16.8 MB)
#define WS_Z        (131072u + 4194304u + 16777216u) // float[4096*1024] (16.8 MB)

// async global->LDS, 16B per lane
__device__ __forceinline__ void gload_lds16(const void* g, void* l) {
    __builtin_amdgcn_global_load_lds(
        (const __attribute__((address_space(1))) unsigned int*)g,
        (__attribute__((address_space(3))) unsigned int*)l, 16, 0, 0);
}

__device__ __forceinline__ bf16x8 cvt8(float4 a, float4 b) {
    bf16x8 r;
    r[0] = (__bf16)a.x; r[1] = (__bf16)a.y; r[2] = (__bf16)a.z; r[3] = (__bf16)a.w;
    r[4] = (__bf16)b.x; r[5] = (__bf16)b.y; r[6] = (__bf16)b.z; r[7] = (__bf16)b.w;
    return r;
}

// swizzled LDS fragment read: tile row-major [rows][64] bf16, 128B rows,
// 16B granule c4 stored at column (c4 ^ (row&7))
__device__ __forceinline__ bf16x8 ldsfrag(const __bf16* base, int row, int c4) {
    return *(const bf16x8*)((const char*)base + row * 128 + ((c4 ^ (row & 7)) << 4));
}

// ---------------- x -> bf16 ----------------
__global__ __launch_bounds__(256) void moe_cvt_x(const float* __restrict__ x,
                                                 __bf16* __restrict__ xb) {
    int i = blockIdx.x * 256 + threadIdx.x;        // 262144 threads, 8 elems each
    const float4* x4 = (const float4*)x + (size_t)i * 2;
    float4 a = x4[0], b = x4[1];
    *(bf16x8*)(xb + (size_t)i * 8) = cvt8(a, b);
}

// ---------------- router (exact fp32): gating GEMV + softmax + top2 ----------------
__global__ __launch_bounds__(256) void moe_router(
    const float* __restrict__ x, const float* __restrict__ rw,
    int* __restrict__ counts, int* __restrict__ sel, float* __restrict__ selw)
{
    int wave = threadIdx.x >> 6;
    int lane = threadIdx.x & 63;
    int t = blockIdx.x * 4 + wave;
    if (t >= T_TOKENS) return;

    const float4* x4  = (const float4*)x + (size_t)t * (HID / 4);
    const float4* rw4 = (const float4*)rw;

    float acc[NE];
#pragma unroll
    for (int e = 0; e < NE; ++e) acc[e] = 0.f;
#pragma unroll
    for (int q = 0; q < 4; ++q) {
        int idx = q * 64 + lane;
        float4 xv = x4[idx];
#pragma unroll
        for (int e = 0; e < NE; ++e) {
            float4 rv = rw4[e * (HID / 4) + idx];
            acc[e] += xv.x * rv.x + xv.y * rv.y + xv.z * rv.z + xv.w * rv.w;
        }
    }
#pragma unroll
    for (int off = 32; off; off >>= 1)
#pragma unroll
        for (int e = 0; e < NE; ++e) acc[e] += __shfl_xor(acc[e], off, 64);

    if (lane == 0) {
        float m = acc[0];
#pragma unroll
        for (int e = 1; e < NE; ++e) m = fmaxf(m, acc[e]);
        float p[NE], s = 0.f;
#pragma unroll
        for (int e = 0; e < NE; ++e) { p[e] = expf(acc[e] - m); s += p[e]; }
        float inv = 1.f / s;
        int i0 = 0;
#pragma unroll
        for (int e = 1; e < NE; ++e) if (p[e] > p[i0]) i0 = e;
        int i1 = (i0 == 0) ? 1 : 0;
#pragma unroll
        for (int e = 0; e < NE; ++e) if (e != i0 && p[e] > p[i1]) i1 = e;
        sel[t * 2 + 0] = i0; selw[t * 2 + 0] = p[i0] * inv;
        sel[t * 2 + 1] = i1; selw[t * 2 + 1] = p[i1] * inv;
        atomicAdd(&counts[i0], 1);
        atomicAdd(&counts[i1], 1);
    }
}

__global__ void moe_scan(const int* __restrict__ counts,
                         int* __restrict__ offsets, int* __restrict__ cursors)
{
    if (threadIdx.x == 0 && blockIdx.x == 0) {
        int off = 0;
        for (int e = 0; e < NE; ++e) { offsets[e] = off; off += counts[e]; cursors[e] = 0; }
    }
}

__global__ __launch_bounds__(256) void moe_assign(
    const int* __restrict__ sel, const float* __restrict__ selw,
    const int* __restrict__ offsets, int* __restrict__ cursors,
    int* __restrict__ row_token, float* __restrict__ row_w,
    int* __restrict__ token_rows)
{
    int t = blockIdx.x * 256 + threadIdx.x;
    if (t >= T_TOKENS) return;
#pragma unroll
    for (int k = 0; k < 2; ++k) {
        int e = sel[t * 2 + k];
        int slot = atomicAdd(&cursors[e], 1);
        int r = offsets[e] + slot;
        row_token[r] = t;
        row_w[r] = selw[t * 2 + k];
        token_rows[t * 2 + k] = r;
    }
}

// ---------------- GEMM1 (bf16 MFMA): y = silu(x*W1g^T) * (x*W1u^T) ----------------
// tile: 128 rows x 64 cols, DUAL (gate+up). BK=64. 4 waves as 2x2 (wave = 64x32).
__global__ __launch_bounds__(256, 2) void moe_gemm1(
    const __bf16* __restrict__ xb, const float* __restrict__ w1,
    const int* __restrict__ row_token, const int* __restrict__ counts,
    const int* __restrict__ offsets, __bf16* __restrict__ y)
{
    int e = blockIdx.z;
    int cnt = counts[e];
    int row0 = blockIdx.y * 128;
    if (row0 >= cnt) return;
    int col0 = blockIdx.x * 64;
    int base = offsets[e];

    __shared__ __bf16 As[128 * 64];
    __shared__ __bf16 Bg[64 * 64];
    __shared__ __bf16 Bu[64 * 64];

    int tid = threadIdx.x;
    int lane = tid & 63;
    int wid = tid >> 6;
    int c4 = lane & 7;                 // 16B granule within 128B row

    // A staging (global_load_lds, linear LDS dest + inverse-swizzled per-lane source)
    const __bf16* srcA[4];
    char* dstA[4];
#pragma unroll
    for (int i = 0; i < 4; ++i) {
        int ii = wid * 4 + i;
        int r = ii * 8 + (lane >> 3);
        int rl = row0 + r; if (rl > cnt - 1) rl = cnt - 1;
        int tok = row_token[base + rl];
        srcA[i] = xb + (size_t)tok * HID + ((c4 ^ (r & 7)) << 3);
        dstA[i] = (char*)As + ii * 1024 + lane * 16;
    }
    // B staging (reg-stage fp32 -> cvt -> swizzled ds_write); 2 passes x 2 tiles
    const float* srcBg[2]; const float* srcBu[2]; int offB[2];
    int tc4 = tid & 7;
#pragma unroll
    for (int p = 0; p < 2; ++p) {
        int rb = p * 32 + (tid >> 3);
        srcBg[p] = w1 + ((size_t)e * 2 * INTER + col0 + rb) * HID + (tc4 << 3);
        srcBu[p] = srcBg[p] + (size_t)INTER * HID;
        offB[p] = rb * 128 + ((tc4 ^ (rb & 7)) << 4);
    }

    int wr = (wid >> 1) * 64, wc = (wid & 1) * 32;
    f32x4 ag[4][2] = {}, au[4][2] = {};

    for (int k0 = 0; k0 < HID; k0 += 64) {
        __syncthreads();
#pragma unroll
        for (int i = 0; i < 4; ++i) gload_lds16(srcA[i] + k0, dstA[i]);
#pragma unroll
        for (int p = 0; p < 2; ++p) {
            float4 g0 = *(const float4*)(srcBg[p] + k0);
            float4 g1 = *(const float4*)(srcBg[p] + k0 + 4);
            float4 u0 = *(const float4*)(srcBu[p] + k0);
            float4 u1 = *(const float4*)(srcBu[p] + k0 + 4);
            *(bf16x8*)((char*)Bg + offB[p]) = cvt8(g0, g1);
            *(bf16x8*)((char*)Bu + offB[p]) = cvt8(u0, u1);
        }
        __syncthreads();
#pragma unroll
        for (int ks = 0; ks < 2; ++ks) {
            int kc4 = ks * 4 + (lane >> 4);
            bf16x8 a[4], bg[2], bu[2];
#pragma unroll
            for (int m = 0; m < 4; ++m) a[m] = ldsfrag(As, wr + m * 16 + (lane & 15), kc4);
#pragma unroll
            for (int n = 0; n < 2; ++n) {
                bg[n] = ldsfrag(Bg, wc + n * 16 + (lane & 15), kc4);
                bu[n] = ldsfrag(Bu, wc + n * 16 + (lane & 15), kc4);
            }
#pragma unroll
            for (int m = 0; m < 4; ++m)
#pragma unroll
                for (int n = 0; n < 2; ++n) {
                    ag[m][n] = __builtin_amdgcn_mfma_f32_16x16x32_bf16(a[m], bg[n], ag[m][n], 0, 0, 0);
                    au[m][n] = __builtin_amdgcn_mfma_f32_16x16x32_bf16(a[m], bu[n], au[m][n], 0, 0, 0);
                }
        }
    }

    // epilogue: silu(g)*u -> bf16 y.  D layout: col=lane&15, row=(lane>>4)*4+j
#pragma unroll
    for (int m = 0; m < 4; ++m) {
#pragma unroll
        for (int j = 0; j < 4; ++j) {
            int rl = wr + m * 16 + ((lane >> 4) << 2) + j;
            if (row0 + rl >= cnt) continue;
            size_t yrow = (size_t)(base + row0 + rl) * INTER;
#pragma unroll
            for (int n = 0; n < 2; ++n) {
                float g = ag[m][n][j], u = au[m][n][j];
                float s = g / (1.f + __expf(-g));
                y[yrow + col0 + wc + n * 16 + (lane & 15)] = (__bf16)(s * u);
            }
        }
    }
}

// ---------------- GEMM2 (bf16 MFMA): z = row_w * (y * W2^T) ----------------
// tile: 128 rows x 64 cols (HID). BK=64, K=2048. 4 waves as 2x2.
__global__ __launch_bounds__(256, 2) void moe_gemm2(
    const __bf16* __restrict__ y, const float* __restrict__ w2,
    const float* __restrict__ row_w, const int* __restrict__ counts,
    const int* __restrict__ offsets, float* __restrict__ z)
{
    int e = blockIdx.z;
    int cnt = counts[e];
    int row0 = blockIdx.y * 128;
    if (row0 >= cnt) return;
    int col0 = blockIdx.x * 64;
    int base = offsets[e];

    __shared__ __bf16 As[128 * 64];
    __shared__ __bf16 Bs[64 * 64];

    int tid = threadIdx.x;
    int lane = tid & 63;
    int wid = tid >> 6;
    int c4 = lane & 7;

    const __bf16* srcA[4];
    char* dstA[4];
#pragma unroll
    for (int i = 0; i < 4; ++i) {
        int ii = wid * 4 + i;
        int r = ii * 8 + (lane >> 3);
        int rl = row0 + r; if (rl > cnt - 1) rl = cnt - 1;
        srcA[i] = y + (size_t)(base + rl) * INTER + ((c4 ^ (r & 7)) << 3);
        dstA[i] = (char*)As + ii * 1024 + lane * 16;
    }
    const float* srcB[2]; int offB[2];
    int tc4 = tid & 7;
#pragma unroll
    for (int p = 0; p < 2; ++p) {
        int rb = p * 32 + (tid >> 3);
        srcB[p] = w2 + ((size_t)e * HID + col0 + rb) * INTER + (tc4 << 3);
        offB[p] = rb * 128 + ((tc4 ^ (rb & 7)) << 4);
    }

    int wr = (wid >> 1) * 64, wc = (wid & 1) * 32;
    f32x4 acc[4][2] = {};

    for (int k0 = 0; k0 < INTER; k0 += 64) {
        __syncthreads();
#pragma unroll
        for (int i = 0; i < 4; ++i) gload_lds16(srcA[i] + k0, dstA[i]);
#pragma unroll
        for (int p = 0; p < 2; ++p) {
            float4 b0 = *(const float4*)(srcB[p] + k0);
            float4 b1 = *(const float4*)(srcB[p] + k0 + 4);
            *(bf16x8*)((char*)Bs + offB[p]) = cvt8(b0, b1);
        }
        __syncthreads();
#pragma unroll
        for (int ks = 0; ks < 2; ++ks) {
            int kc4 = ks * 4 + (lane >> 4);
            bf16x8 a[4], b[2];
#pragma unroll
            for (int m = 0; m < 4; ++m) a[m] = ldsfrag(As, wr + m * 16 + (lane & 15), kc4);
#pragma unroll
            for (int n = 0; n < 2; ++n) b[n] = ldsfrag(Bs, wc + n * 16 + (lane & 15), kc4);
#pragma unroll
            for (int m = 0; m < 4; ++m)
#pragma unroll
                for (int n = 0; n < 2; ++n)
                    acc[m][n] = __builtin_amdgcn_mfma_f32_16x16x32_bf16(a[m], b[n], acc[m][n], 0, 0, 0);
        }
    }

#pragma unroll
    for (int m = 0; m < 4; ++m) {
#pragma unroll
        for (int j = 0; j < 4; ++j) {
            int rl = wr + m * 16 + ((lane >> 4) << 2) + j;
            if (row0 + rl >= cnt) continue;
            float wgt = row_w[base + row0 + rl];
            size_t zrow = (size_t)(base + row0 + rl) * HID;
#pragma unroll
            for (int n = 0; n < 2; ++n)
                z[zrow + col0 + wc + n * 16 + (lane & 15)] = acc[m][n][j] * wgt;
        }
    }
}

// ---------------- combine: out[t] = z[r0] + z[r1] ----------------
__global__ __launch_bounds__(256) void moe_combine(
    const float* __restrict__ z, const int* __restrict__ token_rows,
    float* __restrict__ out)
{
    int total = T_TOKENS * (HID / 4);
    for (int idx = blockIdx.x * 256 + threadIdx.x; idx < total; idx += gridDim.x * 256) {
        int t  = idx >> 8;
        int h4 = idx & 255;
        int r0 = token_rows[t * 2 + 0];
        int r1 = token_rows[t * 2 + 1];
        const float4* z4 = (const float4*)z;
        float4 a = z4[(size_t)r0 * 256 + h4];
        float4 b = z4[(size_t)r1 * 256 + h4];
        float4 o = {a.x + b.x, a.y + b.y, a.z + b.z, a.w + b.w};
        ((float4*)out)[(size_t)t * 256 + h4] = o;
    }
}

extern "C" void kernel_launch(void* const* d_in, const int* in_sizes, int n_in,
                              void* d_out, int out_size, void* d_ws, size_t ws_size,
                              hipStream_t stream) {
    const float* x  = (const float*)d_in[0];   // [1,2048,1024]
    const float* w1 = (const float*)d_in[1];   // [8,4096,1024]
    const float* w2 = (const float*)d_in[2];   // [8,1024,2048]
    const float* rw = (const float*)d_in[3];   // [8,1024]
    float* out = (float*)d_out;

    char* ws = (char*)d_ws;
    int*    counts     = (int*)(ws + WS_COUNTS);
    int*    cursors    = (int*)(ws + WS_CURSORS);
    int*    offsets    = (int*)(ws + WS_OFFSETS);
    int*    sel        = (int*)(ws + WS_SEL);
    float*  selw       = (float*)(ws + WS_SELW);
    int*    row_token  = (int*)(ws + WS_ROWTOK);
    float*  row_w      = (float*)(ws + WS_ROWW);
    int*    token_rows = (int*)(ws + WS_TOKROWS);
    __bf16* xb         = (__bf16*)(ws + WS_XB);
    __bf16* y          = (__bf16*)(ws + WS_Y);
    float*  z          = (float*)(ws + WS_Z);

    hipMemsetAsync(ws, 0, 128, stream);

    moe_cvt_x<<<1024, 256, 0, stream>>>(x, xb);
    moe_router<<<T_TOKENS / 4, 256, 0, stream>>>(x, rw, counts, sel, selw);
    moe_scan<<<1, 64, 0, stream>>>(counts, offsets, cursors);
    moe_assign<<<T_TOKENS / 256, 256, 0, stream>>>(sel, selw, offsets, cursors,
                                                   row_token, row_w, token_rows);
    moe_gemm1<<<dim3(INTER / 64, 16, NE), 256, 0, stream>>>(
        xb, w1, row_token, counts, offsets, y);
    moe_gemm2<<<dim3(HID / 64, 16, NE), 256, 0, stream>>>(
        y, w2, row_w, counts, offsets, z);
    moe_combine<<<1024, 256, 0, stream>>>(z, token_rows, out);
}

// Round 6
// 407.746 us; speedup vs baseline: 2.7760x; 1.0882x over previous
//
#include <hip/hip_runtime.h>
#include <hip/hip_bf16.h>
#include <math.h>

#define T_TOKENS 2048
#define HID 1024
#define INTER 2048
#define NE 8

typedef __attribute__((ext_vector_type(8))) __bf16 bf16x8;
typedef __attribute__((ext_vector_type(4))) __bf16 bf16x4;
typedef __attribute__((ext_vector_type(4))) float f32x4;

// ---------------- workspace layout (bytes) ----------------
#define WS_COUNTS   0u          // int[8]
#define WS_OFFSETS  64u         // int[8]
#define WS_SEL      128u        // int[4096]
#define WS_SELW     16512u      // float[4096]
#define WS_ROWTOK   32896u      // int[4096]
#define WS_ROWW     49280u      // float[4096]
#define WS_TOKROWS  65664u      // int[4096]
#define WS_XB       131072u                      // bf16[2048*1024]  (4 MB)
#define WS_Y        (131072u + 4194304u)         // bf16[4096*2048]  (16.8 MB)
#define WS_Z        (131072u + 4194304u + 16777216u) // float[4096*1024] (16.8 MB)

// async global->LDS, 16B per lane
__device__ __forceinline__ void gload_lds16(const void* g, void* l) {
    __builtin_amdgcn_global_load_lds(
        (const __attribute__((address_space(1))) unsigned int*)g,
        (__attribute__((address_space(3))) unsigned int*)l, 16, 0, 0);
}

__device__ __forceinline__ bf16x8 cvt8(float4 a, float4 b) {
    bf16x8 r;
    r[0] = (__bf16)a.x; r[1] = (__bf16)a.y; r[2] = (__bf16)a.z; r[3] = (__bf16)a.w;
    r[4] = (__bf16)b.x; r[5] = (__bf16)b.y; r[6] = (__bf16)b.z; r[7] = (__bf16)b.w;
    return r;
}

// swizzled LDS fragment read: tile row-major [rows][64] bf16, 128B rows,
// 16B granule c4 stored at column (c4 ^ (row&7))
__device__ __forceinline__ bf16x8 ldsfrag(const __bf16* base, int row, int c4) {
    return *(const bf16x8*)((const char*)base + row * 128 + ((c4 ^ (row & 7)) << 4));
}

// ---------------- router (exact fp32) + fused x->bf16 conversion ----------------
__global__ __launch_bounds__(256) void moe_router(
    const float* __restrict__ x, const float* __restrict__ rw,
    int* __restrict__ counts, int* __restrict__ sel, float* __restrict__ selw,
    __bf16* __restrict__ xb)
{
    int wave = threadIdx.x >> 6;
    int lane = threadIdx.x & 63;
    int t = blockIdx.x * 4 + wave;
    if (t >= T_TOKENS) return;

    const float4* x4  = (const float4*)x + (size_t)t * (HID / 4);
    const float4* rw4 = (const float4*)rw;

    float acc[NE];
#pragma unroll
    for (int e = 0; e < NE; ++e) acc[e] = 0.f;
#pragma unroll
    for (int q = 0; q < 4; ++q) {
        int idx = q * 64 + lane;
        float4 xv = x4[idx];
        // fused bf16 conversion store (x is read anyway)
        bf16x4 c;
        c[0] = (__bf16)xv.x; c[1] = (__bf16)xv.y; c[2] = (__bf16)xv.z; c[3] = (__bf16)xv.w;
        *(bf16x4*)(xb + (size_t)t * HID + idx * 4) = c;
#pragma unroll
        for (int e = 0; e < NE; ++e) {
            float4 rv = rw4[e * (HID / 4) + idx];
            acc[e] += xv.x * rv.x + xv.y * rv.y + xv.z * rv.z + xv.w * rv.w;
        }
    }
#pragma unroll
    for (int off = 32; off; off >>= 1)
#pragma unroll
        for (int e = 0; e < NE; ++e) acc[e] += __shfl_xor(acc[e], off, 64);

    if (lane == 0) {
        float m = acc[0];
#pragma unroll
        for (int e = 1; e < NE; ++e) m = fmaxf(m, acc[e]);
        float p[NE], s = 0.f;
#pragma unroll
        for (int e = 0; e < NE; ++e) { p[e] = expf(acc[e] - m); s += p[e]; }
        float inv = 1.f / s;
        int i0 = 0;
#pragma unroll
        for (int e = 1; e < NE; ++e) if (p[e] > p[i0]) i0 = e;
        int i1 = (i0 == 0) ? 1 : 0;
#pragma unroll
        for (int e = 0; e < NE; ++e) if (e != i0 && p[e] > p[i1]) i1 = e;
        sel[t * 2 + 0] = i0; selw[t * 2 + 0] = p[i0] * inv;
        sel[t * 2 + 1] = i1; selw[t * 2 + 1] = p[i1] * inv;
        atomicAdd(&counts[i0], 1);
        atomicAdd(&counts[i1], 1);
    }
}

// ---------------- fused scan + slot assignment (single block) ----------------
__global__ __launch_bounds__(256) void moe_scan_assign(
    const int* __restrict__ counts, int* __restrict__ offsets,
    const int* __restrict__ sel, const float* __restrict__ selw,
    int* __restrict__ row_token, float* __restrict__ row_w,
    int* __restrict__ token_rows)
{
    __shared__ int soff[NE];
    __shared__ int scur[NE];
    if (threadIdx.x == 0) {
        int off = 0;
        for (int e = 0; e < NE; ++e) { soff[e] = off; off += counts[e]; }
    }
    if (threadIdx.x < NE) scur[threadIdx.x] = 0;
    __syncthreads();
    if (threadIdx.x < NE) offsets[threadIdx.x] = soff[threadIdx.x];
    for (int t = threadIdx.x; t < T_TOKENS; t += 256) {
#pragma unroll
        for (int k = 0; k < 2; ++k) {
            int e = sel[t * 2 + k];
            int slot = atomicAdd(&scur[e], 1);
            int r = soff[e] + slot;
            row_token[r] = t;
            row_w[r] = selw[t * 2 + k];
            token_rows[t * 2 + k] = r;
        }
    }
}

// ---------------- GEMM1 (bf16 MFMA, dbuf pipeline): y = silu(x*W1g^T)*(x*W1u^T) ----
// tile: 128 rows x 64 cols DUAL (gate+up). BK=64, NT=16. 4 waves as 2x2.
// Pipeline: stage(t+1) issued at top, compute(t), B ds_write late, ONE barrier/step.
__global__ __launch_bounds__(256, 2) void moe_gemm1(
    const __bf16* __restrict__ xb, const float* __restrict__ w1,
    const int* __restrict__ row_token, const int* __restrict__ counts,
    const int* __restrict__ offsets, __bf16* __restrict__ y)
{
    int e = blockIdx.z;
    int cnt = counts[e];
    int row0 = blockIdx.y * 128;
    if (row0 >= cnt) return;
    int col0 = blockIdx.x * 64;
    int base = offsets[e];

    __shared__ __bf16 As[2][128 * 64];
    __shared__ __bf16 Bg[2][64 * 64];
    __shared__ __bf16 Bu[2][64 * 64];

    int tid = threadIdx.x;
    int lane = tid & 63;
    int wid = tid >> 6;
    int c4 = lane & 7;

    // A staging (global_load_lds, linear LDS dest + inverse-swizzled per-lane source)
    const __bf16* srcA[4];
    int dstA[4];
#pragma unroll
    for (int i = 0; i < 4; ++i) {
        int ii = wid * 4 + i;
        int r = ii * 8 + (lane >> 3);
        int rl = row0 + r; if (rl > cnt - 1) rl = cnt - 1;
        int tok = row_token[base + rl];
        srcA[i] = xb + (size_t)tok * HID + ((c4 ^ (r & 7)) << 3);
        dstA[i] = ii * 1024 + lane * 16;     // byte offset within tile
    }
    // B staging (reg-stage fp32 -> cvt -> swizzled ds_write)
    const float* srcBg[2]; const float* srcBu[2]; int offB[2];
    int tc4 = tid & 7;
#pragma unroll
    for (int p = 0; p < 2; ++p) {
        int rb = p * 32 + (tid >> 3);
        srcBg[p] = w1 + ((size_t)e * 2 * INTER + col0 + rb) * HID + (tc4 << 3);
        srcBu[p] = srcBg[p] + (size_t)INTER * HID;
        offB[p] = rb * 128 + ((tc4 ^ (rb & 7)) << 4);
    }

    // ---- prologue: stage tile 0 into buffer 0 ----
#pragma unroll
    for (int i = 0; i < 4; ++i) gload_lds16(srcA[i], (char*)As[0] + dstA[i]);
#pragma unroll
    for (int p = 0; p < 2; ++p) {
        float4 g0 = *(const float4*)(srcBg[p]);
        float4 g1 = *(const float4*)(srcBg[p] + 4);
        float4 u0 = *(const float4*)(srcBu[p]);
        float4 u1 = *(const float4*)(srcBu[p] + 4);
        *(bf16x8*)((char*)Bg[0] + offB[p]) = cvt8(g0, g1);
        *(bf16x8*)((char*)Bu[0] + offB[p]) = cvt8(u0, u1);
    }
    __syncthreads();

    int wr = (wid >> 1) * 64, wc = (wid & 1) * 32;
    f32x4 ag[4][2] = {}, au[4][2] = {};

    for (int t = 0; t < 16; ++t) {
        int cur = t & 1;
        float4 g0[2], g1[2], u0[2], u1[2];
        bool pre = (t < 15);
        if (pre) {
            int k0 = (t + 1) * 64;
#pragma unroll
            for (int i = 0; i < 4; ++i)
                gload_lds16(srcA[i] + k0, (char*)As[cur ^ 1] + dstA[i]);
#pragma unroll
            for (int p = 0; p < 2; ++p) {
                g0[p] = *(const float4*)(srcBg[p] + k0);
                g1[p] = *(const float4*)(srcBg[p] + k0 + 4);
                u0[p] = *(const float4*)(srcBu[p] + k0);
                u1[p] = *(const float4*)(srcBu[p] + k0 + 4);
            }
        }
        const __bf16* Ab = As[cur];
        const __bf16* Bgb = Bg[cur];
        const __bf16* Bub = Bu[cur];
#pragma unroll
        for (int ks = 0; ks < 2; ++ks) {
            int kc4 = ks * 4 + (lane >> 4);
            bf16x8 a[4], bg[2], bu[2];
#pragma unroll
            for (int m = 0; m < 4; ++m) a[m] = ldsfrag(Ab, wr + m * 16 + (lane & 15), kc4);
#pragma unroll
            for (int n = 0; n < 2; ++n) {
                bg[n] = ldsfrag(Bgb, wc + n * 16 + (lane & 15), kc4);
                bu[n] = ldsfrag(Bub, wc + n * 16 + (lane & 15), kc4);
            }
#pragma unroll
            for (int m = 0; m < 4; ++m)
#pragma unroll
                for (int n = 0; n < 2; ++n) {
                    ag[m][n] = __builtin_amdgcn_mfma_f32_16x16x32_bf16(a[m], bg[n], ag[m][n], 0, 0, 0);
                    au[m][n] = __builtin_amdgcn_mfma_f32_16x16x32_bf16(a[m], bu[n], au[m][n], 0, 0, 0);
                }
        }
        if (pre) {
#pragma unroll
            for (int p = 0; p < 2; ++p) {
                *(bf16x8*)((char*)Bg[cur ^ 1] + offB[p]) = cvt8(g0[p], g1[p]);
                *(bf16x8*)((char*)Bu[cur ^ 1] + offB[p]) = cvt8(u0[p], u1[p]);
            }
        }
        __syncthreads();
    }

    // epilogue: silu(g)*u -> bf16 y.  D layout: col=lane&15, row=(lane>>4)*4+j
#pragma unroll
    for (int m = 0; m < 4; ++m) {
#pragma unroll
        for (int j = 0; j < 4; ++j) {
            int rl = wr + m * 16 + ((lane >> 4) << 2) + j;
            if (row0 + rl >= cnt) continue;
            size_t yrow = (size_t)(base + row0 + rl) * INTER;
#pragma unroll
            for (int n = 0; n < 2; ++n) {
                float g = ag[m][n][j], u = au[m][n][j];
                float s = g / (1.f + __expf(-g));
                y[yrow + col0 + wc + n * 16 + (lane & 15)] = (__bf16)(s * u);
            }
        }
    }
}

// ---------------- GEMM2 (bf16 MFMA, dbuf pipeline): z = row_w * (y * W2^T) ------
// tile: 128 rows x 64 cols (HID). BK=64, NT=32. 4 waves as 2x2.
__global__ __launch_bounds__(256, 3) void moe_gemm2(
    const __bf16* __restrict__ y, const float* __restrict__ w2,
    const float* __restrict__ row_w, const int* __restrict__ counts,
    const int* __restrict__ offsets, float* __restrict__ z)
{
    int e = blockIdx.z;
    int cnt = counts[e];
    int row0 = blockIdx.y * 128;
    if (row0 >= cnt) return;
    int col0 = blockIdx.x * 64;
    int base = offsets[e];

    __shared__ __bf16 As[2][128 * 64];
    __shared__ __bf16 Bs[2][64 * 64];

    int tid = threadIdx.x;
    int lane = tid & 63;
    int wid = tid >> 6;
    int c4 = lane & 7;

    const __bf16* srcA[4];
    int dstA[4];
#pragma unroll
    for (int i = 0; i < 4; ++i) {
        int ii = wid * 4 + i;
        int r = ii * 8 + (lane >> 3);
        int rl = row0 + r; if (rl > cnt - 1) rl = cnt - 1;
        srcA[i] = y + (size_t)(base + rl) * INTER + ((c4 ^ (r & 7)) << 3);
        dstA[i] = ii * 1024 + lane * 16;
    }
    const float* srcB[2]; int offB[2];
    int tc4 = tid & 7;
#pragma unroll
    for (int p = 0; p < 2; ++p) {
        int rb = p * 32 + (tid >> 3);
        srcB[p] = w2 + ((size_t)e * HID + col0 + rb) * INTER + (tc4 << 3);
        offB[p] = rb * 128 + ((tc4 ^ (rb & 7)) << 4);
    }

    // ---- prologue ----
#pragma unroll
    for (int i = 0; i < 4; ++i) gload_lds16(srcA[i], (char*)As[0] + dstA[i]);
#pragma unroll
    for (int p = 0; p < 2; ++p) {
        float4 b0 = *(const float4*)(srcB[p]);
        float4 b1 = *(const float4*)(srcB[p] + 4);
        *(bf16x8*)((char*)Bs[0] + offB[p]) = cvt8(b0, b1);
    }
    __syncthreads();

    int wr = (wid >> 1) * 64, wc = (wid & 1) * 32;
    f32x4 acc[4][2] = {};

    for (int t = 0; t < 32; ++t) {
        int cur = t & 1;
        float4 b0[2], b1[2];
        bool pre = (t < 31);
        if (pre) {
            int k0 = (t + 1) * 64;
#pragma unroll
            for (int i = 0; i < 4; ++i)
                gload_lds16(srcA[i] + k0, (char*)As[cur ^ 1] + dstA[i]);
#pragma unroll
            for (int p = 0; p < 2; ++p) {
                b0[p] = *(const float4*)(srcB[p] + k0);
                b1[p] = *(const float4*)(srcB[p] + k0 + 4);
            }
        }
        const __bf16* Ab = As[cur];
        const __bf16* Bb = Bs[cur];
#pragma unroll
        for (int ks = 0; ks < 2; ++ks) {
            int kc4 = ks * 4 + (lane >> 4);
            bf16x8 a[4], b[2];
#pragma unroll
            for (int m = 0; m < 4; ++m) a[m] = ldsfrag(Ab, wr + m * 16 + (lane & 15), kc4);
#pragma unroll
            for (int n = 0; n < 2; ++n) b[n] = ldsfrag(Bb, wc + n * 16 + (lane & 15), kc4);
#pragma unroll
            for (int m = 0; m < 4; ++m)
#pragma unroll
                for (int n = 0; n < 2; ++n)
                    acc[m][n] = __builtin_amdgcn_mfma_f32_16x16x32_bf16(a[m], b[n], acc[m][n], 0, 0, 0);
        }
        if (pre) {
#pragma unroll
            for (int p = 0; p < 2; ++p)
                *(bf16x8*)((char*)Bs[cur ^ 1] + offB[p]) = cvt8(b0[p], b1[p]);
        }
        __syncthreads();
    }

#pragma unroll
    for (int m = 0; m < 4; ++m) {
#pragma unroll
        for (int j = 0; j < 4; ++j) {
            int rl = wr + m * 16 + ((lane >> 4) << 2) + j;
            if (row0 + rl >= cnt) continue;
            float wgt = row_w[base + row0 + rl];
            size_t zrow = (size_t)(base + row0 + rl) * HID;
#pragma unroll
            for (int n = 0; n < 2; ++n)
                z[zrow + col0 + wc + n * 16 + (lane & 15)] = acc[m][n][j] * wgt;
        }
    }
}

// ---------------- combine: out[t] = z[r0] + z[r1] ----------------
__global__ __launch_bounds__(256) void moe_combine(
    const float* __restrict__ z, const int* __restrict__ token_rows,
    float* __restrict__ out)
{
    int total = T_TOKENS * (HID / 4);
    for (int idx = blockIdx.x * 256 + threadIdx.x; idx < total; idx += gridDim.x * 256) {
        int t  = idx >> 8;
        int h4 = idx & 255;
        int r0 = token_rows[t * 2 + 0];
        int r1 = token_rows[t * 2 + 1];
        const float4* z4 = (const float4*)z;
        float4 a = z4[(size_t)r0 * 256 + h4];
        float4 b = z4[(size_t)r1 * 256 + h4];
        float4 o = {a.x + b.x, a.y + b.y, a.z + b.z, a.w + b.w};
        ((float4*)out)[(size_t)t * 256 + h4] = o;
    }
}

extern "C" void kernel_launch(void* const* d_in, const int* in_sizes, int n_in,
                              void* d_out, int out_size, void* d_ws, size_t ws_size,
                              hipStream_t stream) {
    const float* x  = (const float*)d_in[0];   // [1,2048,1024]
    const float* w1 = (const float*)d_in[1];   // [8,4096,1024]
    const float* w2 = (const float*)d_in[2];   // [8,1024,2048]
    const float* rw = (const float*)d_in[3];   // [8,1024]
    float* out = (float*)d_out;

    char* ws = (char*)d_ws;
    int*    counts     = (int*)(ws + WS_COUNTS);
    int*    offsets    = (int*)(ws + WS_OFFSETS);
    int*    sel        = (int*)(ws + WS_SEL);
    float*  selw       = (float*)(ws + WS_SELW);
    int*    row_token  = (int*)(ws + WS_ROWTOK);
    float*  row_w      = (float*)(ws + WS_ROWW);
    int*    token_rows = (int*)(ws + WS_TOKROWS);
    __bf16* xb         = (__bf16*)(ws + WS_XB);
    __bf16* y          = (__bf16*)(ws + WS_Y);
    float*  z          = (float*)(ws + WS_Z);

    hipMemsetAsync(ws, 0, 128, stream);

    moe_router<<<T_TOKENS / 4, 256, 0, stream>>>(x, rw, counts, sel, selw, xb);
    moe_scan_assign<<<1, 256, 0, stream>>>(counts, offsets, sel, selw,
                                           row_token, row_w, token_rows);
    moe_gemm1<<<dim3(INTER / 64, 16, NE), 256, 0, stream>>>(
        xb, w1, row_token, counts, offsets, y);
    moe_gemm2<<<dim3(HID / 64, 16, NE), 256, 0, stream>>>(
        y, w2, row_w, counts, offsets, z);
    moe_combine<<<1024, 256, 0, stream>>>(z, token_rows, out);
}